// Round 3
// baseline (580.991 us; speedup 1.0000x reference)
//
#include <hip/hip_runtime.h>

#define NELEM 131072
#define BSETS 32768
#define DIM 128
#define HID 64
#define MAXP 17

typedef __attribute__((ext_vector_type(8))) short short8;
typedef __attribute__((ext_vector_type(4))) float f32x4;

__device__ __forceinline__ unsigned short f2bf(float f) {
  unsigned u = __float_as_uint(f);
  u += 0x7fff + ((u >> 16) & 1);   // RNE
  return (unsigned short)(u >> 16);
}

__device__ __forceinline__ float bf2f(unsigned short h) {
  return __uint_as_float((unsigned)h << 16);
}

// tanh(x) = 1 - 2/(exp(2x)+1); max err ~1e-6.
__device__ __forceinline__ float fast_tanh(float x) {
  float t = __expf(2.0f * x);
  float r = __builtin_amdgcn_rcpf(t + 1.0f);
  return fmaf(-2.0f, r, 1.0f);
}

// ---------------- positional-encoder tables (17->40 LN tanh ->64) ----------------
__device__ void pos_mlp40(int row, const float* w1, const float* b1, const float* g,
                          const float* bt, const float* w2, const float* b2, float* out) {
  float h[40];
  for (int j = 0; j < 40; ++j) h[j] = b1[j] + (row >= 0 ? w1[row * 40 + j] : 0.0f);
  float s = 0.f;
  for (int j = 0; j < 40; ++j) s += h[j];
  float mean = s * (1.0f / 40.0f);
  float v = 0.f;
  for (int j = 0; j < 40; ++j) { float d = h[j] - mean; v += d * d; }
  float rs = rsqrtf(v * (1.0f / 40.0f) + 1e-5f);
  float tb[40];
  for (int j = 0; j < 40; ++j) tb[j] = fast_tanh((h[j] - mean) * rs * g[j] + bt[j]);
  for (int o = 0; o < 64; ++o) {
    float a = b2[o];
    for (int j = 0; j < 40; ++j) a += tb[j] * w2[j * 64 + o];
    out[o] = a;
  }
}

// ---------------- fused init: bounds | pe tables | weight swizzles ----------------
__global__ __launch_bounds__(256) void k_init(
    const int* __restrict__ batch, int* __restrict__ start,
    const float* ew1, const float* eb1, const float* eg, const float* ebt,
    const float* ew2, const float* eb2,
    const float* dw1, const float* db1, const float* dg, const float* dbt,
    const float* dw2, const float* db2,
    float* enc_tab, float* dec_tab,
    const float* __restrict__ decw1, const float* __restrict__ decw2,
    unsigned short* __restrict__ w1s, unsigned short* __restrict__ w2s,
    const float* __restrict__ psiw1, const float* __restrict__ psiw2,
    unsigned short* __restrict__ pw1h, unsigned short* __restrict__ pw1l,
    unsigned short* __restrict__ pw2h, unsigned short* __restrict__ pw2l) {
  int blk = blockIdx.x;
  int t = threadIdx.x;
  if (blk < 512) {                        // ---- bounds ----
    int i = blk * 256 + t;
    int b = batch[i];
    if (i == 0) {
      for (int bb = 0; bb <= b; ++bb) start[bb] = 0;
    } else {
      int bp = batch[i - 1];
      for (int bb = bp + 1; bb <= b; ++bb) start[bb] = i;
    }
    if (i == NELEM - 1) {
      for (int bb = b + 1; bb <= BSETS; ++bb) start[bb] = NELEM;
    }
  } else if (blk == 512) {                // ---- pe tables ----
    if (t < 18) {
      float out[64];
      pos_mlp40(t < 17 ? t : -1, ew1, eb1, eg, ebt, ew2, eb2, out);
      for (int o = 0; o < 64; ++o) enc_tab[t * 64 + o] = out[o];
    } else if (t >= 32 && t < 49) {
      float out[64];
      pos_mlp40(t - 32, dw1, db1, dg, dbt, dw2, db2, out);
      for (int o = 0; o < 64; ++o) dec_tab[(t - 32) * 64 + o] = out[o];
    }
  } else {                                // ---- weight swizzles (MFMA B-fragment layout) ----
    int idx = (blk - 513) * 256 + t;
    if (idx < 6144) {   // dec_w1: 64x96, 2 ksteps x 6 ntiles
      int i = idx & 7, lane = (idx >> 3) & 63, rest = idx >> 9;
      int jt = rest % 6, s = rest / 6;
      int k = s * 32 + (lane >> 4) * 8 + i;
      int n = jt * 16 + (lane & 15);
      w1s[idx] = f2bf(decw1[k * 96 + n]);
    }
    int idx2 = idx - 6144;
    if (idx2 >= 0 && idx2 < 12288) {  // dec_w2: 96x128, 3 ksteps x 8 ntiles
      int i = idx2 & 7, lane = (idx2 >> 3) & 63, rest = idx2 >> 9;
      int jt = rest % 8, s = rest / 8;
      int k = s * 32 + (lane >> 4) * 8 + i;
      int n = jt * 16 + (lane & 15);
      w2s[idx2] = f2bf(decw2[k * 128 + n]);
    }
    int idx3 = idx - 18432;
    if (idx3 >= 0 && idx3 < 12288) {  // psi_w1: 128x96 hi/lo, 4 ksteps x 6 ntiles
      int i = idx3 & 7, lane = (idx3 >> 3) & 63, rest = idx3 >> 9;
      int jt = rest % 6, s = rest / 6;
      int k = s * 32 + (lane >> 4) * 8 + i;
      int n = jt * 16 + (lane & 15);
      float v = psiw1[k * 96 + n];
      unsigned short h = f2bf(v);
      pw1h[idx3] = h;
      pw1l[idx3] = f2bf(v - bf2f(h));
    }
    int idx4 = idx - 30720;
    if (idx4 >= 0 && idx4 < 6144) {   // psi_w2: 96x64 hi/lo, 3 ksteps x 4 ntiles
      int i = idx4 & 7, lane = (idx4 >> 3) & 63, rest = idx4 >> 9;
      int nt = rest % 4, s = rest / 4;
      int k = s * 32 + (lane >> 4) * 8 + i;
      int n = nt * 16 + (lane & 15);
      float v = psiw2[k * 64 + n];
      unsigned short h = f2bf(v);
      pw2h[idx4] = h;
      pw2l[idx4] = f2bf(v - bf2f(h));
    }
  }
}

// ---------------- encoder: fused mag(halo) + rank + psi MLP via split-bf16 MFMA ----------------
// mag: segments span <=16 rows (MAXP=17 => n<=16), so all segments touching this
// block's 64 rows live in [base-16, base+80). Compute those 96 mags into LDS with a
// bit-deterministic fp64 butterfly (identical instruction sequence in every block, so
// halo rows recomputed by adjacent blocks get identical values -> consistent ranks).
// MLP: C = Ah*Bh + Ah*Bl + Al*Bh (split-bf16, rel err ~1e-5); LN in MFMA C-layout.
__global__ __launch_bounds__(256) void k_encoder(
    const float* __restrict__ x, const int* __restrict__ batch,
    const float* __restrict__ rank_w, const float* __restrict__ rank_b,
    const int* __restrict__ start,
    const unsigned short* __restrict__ w1h, const unsigned short* __restrict__ w1l,
    const float* __restrict__ b1, const float* __restrict__ g, const float* __restrict__ bt,
    const unsigned short* __restrict__ w2h, const unsigned short* __restrict__ w2l,
    const float* __restrict__ b2,
    const float* __restrict__ enc_tab, float* __restrict__ y1) {
  __shared__ float tt[64][100];   // stride 100 dwords: 16B-aligned rows, 2-way-bank-free
  __shared__ double mlds[96];
  __shared__ int pos_s[64];
  __shared__ int row_s[64];
  int t = threadIdx.x;
  int lane = t & 63;
  int w = __builtin_amdgcn_readfirstlane(t >> 6);
  int base = blockIdx.x * 64;
  int hbase = base - 16;
  int r = lane & 15, gq = lane >> 4;

  {  // ---- mag stage: wave w computes halo rows [w*24, w*24+24) ----
    float2 wv = ((const float2*)rank_w)[lane];
    double w0 = wv.x, w1d = wv.y;
    double rb = rank_b[0];
    for (int it = 0; it < 24; ++it) {
      int hr = w * 24 + it;
      int row = hbase + hr;
      if (row >= 0 && row < NELEM) {
        float2 xv = ((const float2*)(x + (size_t)row * DIM))[lane];
        double acc = (double)xv.x * w0 + (double)xv.y * w1d;
#pragma unroll
        for (int m = 1; m < 64; m <<= 1)
          acc += __shfl_xor(acc, m, 64);
        if (lane == 0) mlds[hr] = acc + rb;
      }
    }
  }
  __syncthreads();

  if (w == 0) {   // ---- rank for the block's 64 rows (one lane per row) ----
    int gi = base + lane;
    int b = batch[gi];
    int segs = start[b], sege = start[b + 1];
    double mi = mlds[gi - hbase];
    int kk = 0;
    for (int j = segs; j < sege; ++j) {
      double mj = mlds[j - hbase];
      kk += (mj < mi) || (mj == mi && j < gi);
    }
    pos_s[lane] = segs + kk;
    row_s[lane] = kk < MAXP ? kk : MAXP;
  }

  // ---- A fragments: x rows of this wave's M-tile, split hi/lo ----
  const float* xr = x + (size_t)(base + w * 16 + r) * DIM + gq * 8;
  short8 ah[4], al[4];
#pragma unroll
  for (int s = 0; s < 4; ++s) {
    float4 v0 = *(const float4*)(xr + s * 32);
    float4 v1 = *(const float4*)(xr + s * 32 + 4);
    float vv[8] = {v0.x, v0.y, v0.z, v0.w, v1.x, v1.y, v1.z, v1.w};
#pragma unroll
    for (int i = 0; i < 8; ++i) {
      unsigned short h = f2bf(vv[i]);
      ((unsigned short*)&ah[s])[i] = h;
      ((unsigned short*)&al[s])[i] = f2bf(vv[i] - bf2f(h));
    }
  }

  // ---- GEMM1: h[64x96] ----
  const short8* W1H = (const short8*)w1h;
  const short8* W1L = (const short8*)w1l;
  f32x4 acc1[6] = {};
#pragma unroll
  for (int jt = 0; jt < 6; ++jt) {
#pragma unroll
    for (int s = 0; s < 4; ++s) {
      short8 bh = W1H[(s * 6 + jt) * 64 + lane];
      short8 bl = W1L[(s * 6 + jt) * 64 + lane];
      acc1[jt] = __builtin_amdgcn_mfma_f32_16x16x32_bf16(ah[s], bh, acc1[jt], 0, 0, 0);
      acc1[jt] = __builtin_amdgcn_mfma_f32_16x16x32_bf16(ah[s], bl, acc1[jt], 0, 0, 0);
      acc1[jt] = __builtin_amdgcn_mfma_f32_16x16x32_bf16(al[s], bh, acc1[jt], 0, 0, 0);
    }
  }

  // ---- bias + LN + tanh in C-layout: lane holds rows gq*4+reg, col jt*16+r ----
  float b1v[6], gv[6], btv[6];
#pragma unroll
  for (int jt = 0; jt < 6; ++jt) {
    b1v[jt] = b1[jt * 16 + r];
    gv[jt] = g[jt * 16 + r];
    btv[jt] = bt[jt * 16 + r];
  }
#pragma unroll
  for (int reg = 0; reg < 4; ++reg) {
    float h[6];
    float s1 = 0.f, s2 = 0.f;
#pragma unroll
    for (int jt = 0; jt < 6; ++jt) {
      h[jt] = acc1[jt][reg] + b1v[jt];
      s1 += h[jt]; s2 += h[jt] * h[jt];
    }
#pragma unroll
    for (int m = 1; m < 16; m <<= 1) {
      s1 += __shfl_xor(s1, m, 64);
      s2 += __shfl_xor(s2, m, 64);
    }
    float mean = s1 * (1.0f / 96.0f);
    float var = s2 * (1.0f / 96.0f) - mean * mean;
    float rs = rsqrtf(var + 1e-5f);
    int rowl = w * 16 + gq * 4 + reg;
#pragma unroll
    for (int jt = 0; jt < 6; ++jt)
      tt[rowl][jt * 16 + r] = fast_tanh((h[jt] - mean) * rs * gv[jt] + btv[jt]);
  }
  __syncthreads();

  // ---- A fragments for GEMM2 from tt (transpose via LDS), split hi/lo ----
  const float* trow = &tt[w * 16 + r][0] + gq * 8;
  short8 a2h[3], a2l[3];
#pragma unroll
  for (int s = 0; s < 3; ++s) {
    float4 u0 = *(const float4*)(trow + s * 32);
    float4 u1 = *(const float4*)(trow + s * 32 + 4);
    float vv[8] = {u0.x, u0.y, u0.z, u0.w, u1.x, u1.y, u1.z, u1.w};
#pragma unroll
    for (int i = 0; i < 8; ++i) {
      unsigned short h = f2bf(vv[i]);
      ((unsigned short*)&a2h[s])[i] = h;
      ((unsigned short*)&a2l[s])[i] = f2bf(vv[i] - bf2f(h));
    }
  }

  // ---- GEMM2: y[64x64] ----
  const short8* W2H = (const short8*)w2h;
  const short8* W2L = (const short8*)w2l;
  f32x4 acc2[4] = {};
#pragma unroll
  for (int nt = 0; nt < 4; ++nt) {
#pragma unroll
    for (int s = 0; s < 3; ++s) {
      short8 bh = W2H[(s * 4 + nt) * 64 + lane];
      short8 bl = W2L[(s * 4 + nt) * 64 + lane];
      acc2[nt] = __builtin_amdgcn_mfma_f32_16x16x32_bf16(a2h[s], bh, acc2[nt], 0, 0, 0);
      acc2[nt] = __builtin_amdgcn_mfma_f32_16x16x32_bf16(a2h[s], bl, acc2[nt], 0, 0, 0);
      acc2[nt] = __builtin_amdgcn_mfma_f32_16x16x32_bf16(a2l[s], bh, acc2[nt], 0, 0, 0);
    }
  }

  // ---- epilogue: bias, pe[rank] multiply, scatter to y1 ----
  float b2v[4];
#pragma unroll
  for (int nt = 0; nt < 4; ++nt) b2v[nt] = b2[nt * 16 + r];
#pragma unroll
  for (int reg = 0; reg < 4; ++reg) {
    int rowl = w * 16 + gq * 4 + reg;
    int pos = pos_s[rowl];
    const float* pe = enc_tab + row_s[rowl] * 64;
    float* yd = y1 + (size_t)pos * 64;
#pragma unroll
    for (int nt = 0; nt < 4; ++nt) {
      int col = nt * 16 + r;
      yd[col] = (acc2[nt][reg] + b2v[nt]) * pe[col];
    }
  }
}

// ---------------- phi (+fused segment-sum) + size_pred + argmax: 64 sets/block ----------------
__global__ __launch_bounds__(256) void k_phi(const float* __restrict__ y1,
                                             const int* __restrict__ start,
                                             const float* __restrict__ w1, const float* __restrict__ b1,
                                             const float* __restrict__ w2, const float* __restrict__ b2,
                                             const float* __restrict__ sw1, const float* __restrict__ sb1,
                                             const float* __restrict__ sw2, const float* __restrict__ sb2,
                                             float* __restrict__ z, int* __restrict__ ndec) {
  __shared__ float yt[64][65];
  __shared__ float tt[64][73];
  __shared__ float zt[64][65];
  __shared__ float st[64][41];
  int t = threadIdx.x;
  int base = blockIdx.x * 64;
  {  // fused segment sum: thread (set s = t>>2, chunk c = t&3), ascending-p order
    int s = t >> 2, c = t & 3;
    int sb = base + s;
    int ps = start[sb], pe = start[sb + 1];
    float acc[16];
#pragma unroll
    for (int i = 0; i < 16; ++i) acc[i] = 0.f;
    for (int p = ps; p < pe; ++p) {
      const float4* row = (const float4*)(y1 + (size_t)p * 64 + c * 16);
#pragma unroll
      for (int q = 0; q < 4; ++q) {
        float4 v = row[q];
        acc[4 * q] += v.x; acc[4 * q + 1] += v.y; acc[4 * q + 2] += v.z; acc[4 * q + 3] += v.w;
      }
    }
#pragma unroll
    for (int i = 0; i < 16; ++i) yt[s][c * 16 + i] = acc[i];
  }
  __syncthreads();
  int lane = t & 63;
  int w = __builtin_amdgcn_readfirstlane(t >> 6);
  int sb = base + lane;
  int nb = start[sb + 1] - start[sb];
  // layer1: 72 hidden = 4 waves x 18
  int j0 = w * 18;
  float acc[18];
#pragma unroll
  for (int jj = 0; jj < 18; ++jj) acc[jj] = b1[j0 + jj];
  for (int k = 0; k < 64; ++k) {
    float yv = yt[lane][k];
#pragma unroll
    for (int jj = 0; jj < 18; ++jj) acc[jj] += yv * w1[k * 72 + j0 + jj];
  }
  if (nb < MAXP) {
    const float* wr = w1 + (64 + nb) * 72 + j0;
#pragma unroll
    for (int jj = 0; jj < 18; ++jj) acc[jj] += wr[jj];
  }
#pragma unroll
  for (int jj = 0; jj < 18; ++jj) tt[lane][j0 + jj] = fast_tanh(acc[jj]);
  __syncthreads();
  // layer2: 64 out = 4 waves x 16
  int o0 = w * 16;
  float acc2[16];
#pragma unroll
  for (int oo = 0; oo < 16; ++oo) acc2[oo] = b2[o0 + oo];
  for (int j = 0; j < 72; ++j) {
    float tv = tt[lane][j];
#pragma unroll
    for (int oo = 0; oo < 16; ++oo) acc2[oo] += tv * w2[j * 64 + o0 + oo];
  }
  float4* zd = (float4*)(z + (size_t)sb * 64 + o0);
#pragma unroll
  for (int q = 0; q < 4; ++q)
    zd[q] = make_float4(acc2[4 * q], acc2[4 * q + 1], acc2[4 * q + 2], acc2[4 * q + 3]);
#pragma unroll
  for (int oo = 0; oo < 16; ++oo) zt[lane][o0 + oo] = acc2[oo];
  __syncthreads();
  // size_pred layer1: 40 hidden = 4 waves x 10
  int s0 = w * 10;
  float hs[10];
#pragma unroll
  for (int jj = 0; jj < 10; ++jj) hs[jj] = sb1[s0 + jj];
  for (int o = 0; o < 64; ++o) {
    float v = zt[lane][o];
#pragma unroll
    for (int jj = 0; jj < 10; ++jj) hs[jj] += v * sw1[o * 40 + s0 + jj];
  }
#pragma unroll
  for (int jj = 0; jj < 10; ++jj) st[lane][s0 + jj] = fast_tanh(hs[jj]);
  __syncthreads();
  // logits + argmax: wave 0 only
  if (w == 0) {
    float lg[17];
#pragma unroll
    for (int l = 0; l < 17; ++l) lg[l] = sb2[l];
    for (int j = 0; j < 40; ++j) {
      float tv = st[lane][j];
#pragma unroll
      for (int l = 0; l < 17; ++l) lg[l] += tv * sw2[j * 17 + l];
    }
    float best = lg[0]; int bi = 0;
#pragma unroll
    for (int l = 1; l < 17; ++l) if (lg[l] > best) { best = lg[l]; bi = l; }
    ndec[sb] = bi;
  }
}

// ---------------- decoder (+fused aux outputs): zp(64)->96 tanh->128, bf16 MFMA ----------------
__global__ __launch_bounds__(256) void k_decoder(
    const float* __restrict__ z, const float* __restrict__ dec_tab,
    const unsigned short* __restrict__ w1s, const unsigned short* __restrict__ w2s,
    const float* __restrict__ b1, const float* __restrict__ b2,
    const int* __restrict__ ndec, float* __restrict__ out0,
    float* __restrict__ out1, float* __restrict__ out2) {
  __shared__ __align__(16) unsigned short h2[64][104];
  int t = threadIdx.x;
  int lane = t & 63;
  int w = __builtin_amdgcn_readfirstlane(t >> 6);
  int quad = lane >> 4, m = lane & 15;
  int r = blockIdx.x * 64 + w * 16 + m;
  int b = r / 17, p = r - b * 17;
  const float4* z4 = (const float4*)(z + (size_t)b * 64);
  const float4* p4 = (const float4*)(dec_tab + p * 64);
  short8 a1[2];
#pragma unroll
  for (int s = 0; s < 2; ++s) {
    int q0 = (s * 32 + quad * 8) >> 2;
    float4 za = z4[q0], zb = z4[q0 + 1];
    float4 pa = p4[q0], pb = p4[q0 + 1];
    unsigned short* ap = (unsigned short*)&a1[s];
    ap[0] = f2bf(za.x * pa.x); ap[1] = f2bf(za.y * pa.y);
    ap[2] = f2bf(za.z * pa.z); ap[3] = f2bf(za.w * pa.w);
    ap[4] = f2bf(zb.x * pb.x); ap[5] = f2bf(zb.y * pb.y);
    ap[6] = f2bf(zb.z * pb.z); ap[7] = f2bf(zb.w * pb.w);
  }
  const short8* w1f = (const short8*)w1s;
  f32x4 acc[6] = {};
#pragma unroll
  for (int jt = 0; jt < 6; ++jt) {
    acc[jt] = __builtin_amdgcn_mfma_f32_16x16x32_bf16(a1[0], w1f[jt * 64 + lane], acc[jt], 0, 0, 0);
    acc[jt] = __builtin_amdgcn_mfma_f32_16x16x32_bf16(a1[1], w1f[(6 + jt) * 64 + lane], acc[jt], 0, 0, 0);
  }
#pragma unroll
  for (int jt = 0; jt < 6; ++jt) {
    int col = jt * 16 + m;
    float bias = b1[col];
#pragma unroll
    for (int reg = 0; reg < 4; ++reg) {
      int rl = w * 16 + quad * 4 + reg;
      h2[rl][col] = f2bf(fast_tanh(acc[jt][reg] + bias));
    }
  }
  __syncthreads();
  short8 a2[3];
#pragma unroll
  for (int s = 0; s < 3; ++s)
    a2[s] = *(const short8*)&h2[w * 16 + m][s * 32 + quad * 8];
  const short8* w2f = (const short8*)w2s;
  f32x4 acc2[8] = {};
#pragma unroll
  for (int nt = 0; nt < 8; ++nt) {
#pragma unroll
    for (int s = 0; s < 3; ++s)
      acc2[nt] = __builtin_amdgcn_mfma_f32_16x16x32_bf16(a2[s], w2f[(s * 8 + nt) * 64 + lane], acc2[nt], 0, 0, 0);
  }
  // hoisted per-row mask
  int rgbase = blockIdx.x * 64 + w * 16 + quad * 4;
  bool mk[4];
#pragma unroll
  for (int reg = 0; reg < 4; ++reg) {
    int rg = rgbase + reg;
    int bb = rg / 17, pp = rg - bb * 17;
    mk[reg] = (pp >= ndec[bb]);
  }
#pragma unroll
  for (int nt = 0; nt < 8; ++nt) {
    int n = nt * 16 + m;
    float bias = b2[n];
#pragma unroll
    for (int reg = 0; reg < 4; ++reg) {
      float v = acc2[nt][reg] + bias;
      if (mk[reg]) v = 0.0f;
      out0[(size_t)(rgbase + reg) * 128 + n] = v;
    }
  }
  if (t < 64) {   // fused aux outputs for this block's 64 rows
    int rg = blockIdx.x * 64 + t;
    int bb = rg / 17, pp = rg - bb * 17;
    out1[rg] = (float)bb;
    out2[rg] = (pp < ndec[bb]) ? 1.0f : 0.0f;
  }
}

extern "C" void kernel_launch(void* const* d_in, const int* in_sizes, int n_in,
                              void* d_out, int out_size, void* d_ws, size_t ws_size,
                              hipStream_t stream) {
  const float* x = (const float*)d_in[0];
  const int* batch = (const int*)d_in[1];
  const float* rank_w = (const float*)d_in[2];
  const float* rank_b = (const float*)d_in[3];
  const float* psi_w1 = (const float*)d_in[4];
  const float* psi_b1 = (const float*)d_in[5];
  const float* psi_g = (const float*)d_in[6];
  const float* psi_bt = (const float*)d_in[7];
  const float* psi_w2 = (const float*)d_in[8];
  const float* psi_b2 = (const float*)d_in[9];
  const float* pe_e_w1 = (const float*)d_in[10];
  const float* pe_e_b1 = (const float*)d_in[11];
  const float* pe_e_g = (const float*)d_in[12];
  const float* pe_e_bt = (const float*)d_in[13];
  const float* pe_e_w2 = (const float*)d_in[14];
  const float* pe_e_b2 = (const float*)d_in[15];
  const float* phi_w1 = (const float*)d_in[16];
  const float* phi_b1 = (const float*)d_in[17];
  const float* phi_w2 = (const float*)d_in[18];
  const float* phi_b2 = (const float*)d_in[19];
  const float* size_w1 = (const float*)d_in[20];
  const float* size_b1 = (const float*)d_in[21];
  const float* size_w2 = (const float*)d_in[22];
  const float* size_b2 = (const float*)d_in[23];
  const float* pe_d_w1 = (const float*)d_in[24];
  const float* pe_d_b1 = (const float*)d_in[25];
  const float* pe_d_g = (const float*)d_in[26];
  const float* pe_d_bt = (const float*)d_in[27];
  const float* pe_d_w2 = (const float*)d_in[28];
  const float* pe_d_b2 = (const float*)d_in[29];
  const float* dec_w1 = (const float*)d_in[30];
  const float* dec_b1 = (const float*)d_in[31];
  const float* dec_w2 = (const float*)d_in[32];
  const float* dec_b2 = (const float*)d_in[33];

  char* ws = (char*)d_ws;
  int* start = (int*)(ws);                                   // 131076 B
  float* enc_tab = (float*)(ws + 0x1C0000);
  float* dec_tab = (float*)(ws + 0x1C2000);
  unsigned short* w1s = (unsigned short*)(ws + 0x1C4000);    // 12 KB
  unsigned short* w2s = (unsigned short*)(ws + 0x1C8000);    // 24 KB
  unsigned short* pw1h = (unsigned short*)(ws + 0x1CE000);   // 24 KB
  unsigned short* pw1l = (unsigned short*)(ws + 0x1D4000);   // 24 KB
  unsigned short* pw2h = (unsigned short*)(ws + 0x1DA000);   // 12 KB
  unsigned short* pw2l = (unsigned short*)(ws + 0x1DD000);   // 12 KB
  float* zbuf = (float*)(ws + 0x200000);                     // 8 MB (live during decoder)
  int* ndec = (int*)(ws + 0xA00000);                         // 128 KB

  float* out0 = (float*)d_out;
  float* out1 = out0 + 71303168;    // B*17*128
  float* out2 = out1 + 557056;      // B*17

  // y1 scratch inside out0: consumed by k_phi before k_decoder overwrites out0
  float* y1 = out0;                  // NELEM*64 f32 = 32 MB

  k_init<<<657, 256, 0, stream>>>(batch, start,
                                  pe_e_w1, pe_e_b1, pe_e_g, pe_e_bt, pe_e_w2, pe_e_b2,
                                  pe_d_w1, pe_d_b1, pe_d_g, pe_d_bt, pe_d_w2, pe_d_b2,
                                  enc_tab, dec_tab, dec_w1, dec_w2, w1s, w2s,
                                  psi_w1, psi_w2, pw1h, pw1l, pw2h, pw2l);
  k_encoder<<<2048, 256, 0, stream>>>(x, batch, rank_w, rank_b, start, pw1h, pw1l,
                                      psi_b1, psi_g, psi_bt, pw2h, pw2l, psi_b2,
                                      enc_tab, y1);
  k_phi<<<512, 256, 0, stream>>>(y1, start, phi_w1, phi_b1, phi_w2, phi_b2,
                                 size_w1, size_b1, size_w2, size_b2, zbuf, ndec);
  k_decoder<<<8704, 256, 0, stream>>>(zbuf, dec_tab, w1s, w2s, dec_b1, dec_b2, ndec,
                                      out0, out1, out2);
}

// Round 4
// 563.833 us; speedup vs baseline: 1.0304x; 1.0304x over previous
//
#include <hip/hip_runtime.h>

#define NELEM 131072
#define BSETS 32768
#define DIM 128
#define HID 64
#define MAXP 17

typedef __attribute__((ext_vector_type(8))) short short8;
typedef __attribute__((ext_vector_type(4))) float f32x4;

__device__ __forceinline__ unsigned short f2bf(float f) {
  unsigned u = __float_as_uint(f);
  u += 0x7fff + ((u >> 16) & 1);   // RNE
  return (unsigned short)(u >> 16);
}

__device__ __forceinline__ float bf2f(unsigned short h) {
  return __uint_as_float((unsigned)h << 16);
}

// tanh(x) = 1 - 2/(exp(2x)+1); max err ~1e-6.
__device__ __forceinline__ float fast_tanh(float x) {
  float t = __expf(2.0f * x);
  float r = __builtin_amdgcn_rcpf(t + 1.0f);
  return fmaf(-2.0f, r, 1.0f);
}

// ---------------- positional-encoder tables (17->40 LN tanh ->64) ----------------
__device__ void pos_mlp40(int row, const float* w1, const float* b1, const float* g,
                          const float* bt, const float* w2, const float* b2, float* out) {
  float h[40];
  for (int j = 0; j < 40; ++j) h[j] = b1[j] + (row >= 0 ? w1[row * 40 + j] : 0.0f);
  float s = 0.f;
  for (int j = 0; j < 40; ++j) s += h[j];
  float mean = s * (1.0f / 40.0f);
  float v = 0.f;
  for (int j = 0; j < 40; ++j) { float d = h[j] - mean; v += d * d; }
  float rs = rsqrtf(v * (1.0f / 40.0f) + 1e-5f);
  float tb[40];
  for (int j = 0; j < 40; ++j) tb[j] = fast_tanh((h[j] - mean) * rs * g[j] + bt[j]);
  for (int o = 0; o < 64; ++o) {
    float a = b2[o];
    for (int j = 0; j < 40; ++j) a += tb[j] * w2[j * 64 + o];
    out[o] = a;
  }
}

// ---------------- fused init: mag | bounds | pe tables | weight swizzles ----------------
__global__ __launch_bounds__(256) void k_init(
    const float* __restrict__ x, const int* __restrict__ batch,
    const float* __restrict__ rank_w, const float* __restrict__ rank_b,
    double* __restrict__ mag, int* __restrict__ start,
    const float* ew1, const float* eb1, const float* eg, const float* ebt,
    const float* ew2, const float* eb2,
    const float* dw1, const float* db1, const float* dg, const float* dbt,
    const float* dw2, const float* db2,
    float* enc_tab, float* dec_tab,
    const float* __restrict__ decw1, const float* __restrict__ decw2,
    unsigned short* __restrict__ w1s, unsigned short* __restrict__ w2s,
    const float* __restrict__ psiw1, const float* __restrict__ psiw2,
    unsigned short* __restrict__ pw1h, unsigned short* __restrict__ pw1l,
    unsigned short* __restrict__ pw2h, unsigned short* __restrict__ pw2l) {
  int blk = blockIdx.x;
  int t = threadIdx.x;
  if (blk < 1024) {     // ---- mag: 4 rows/wave-iter, 16-lane fp64 butterfly ----
    int lane = t & 63;
    int w = t >> 6;
    int grp = lane >> 4;     // which row of the quartet
    int gl = lane & 15;      // lane within 16-lane group
    const float4* rw4 = (const float4*)rank_w;
    float4 wa = rw4[gl * 2], wb = rw4[gl * 2 + 1];
    double rb = rank_b[0];
    int rowbase = (blk * 4 + w) * 32;
    for (int it = 0; it < 8; ++it) {
      int row = rowbase + it * 4 + grp;
      const float4* xr = (const float4*)(x + (size_t)row * DIM);
      float4 xa = xr[gl * 2], xb = xr[gl * 2 + 1];
      double acc = ((double)xa.x * wa.x + (double)xa.y * wa.y)
                 + ((double)xa.z * wa.z + (double)xa.w * wa.w)
                 + ((double)xb.x * wb.x + (double)xb.y * wb.y)
                 + ((double)xb.z * wb.z + (double)xb.w * wb.w);
#pragma unroll
      for (int m = 1; m < 16; m <<= 1)
        acc += __shfl_xor(acc, m, 64);
      if (gl == 0) mag[row] = acc + rb;
    }
  } else if (blk < 1536) {                // ---- bounds ----
    int i = (blk - 1024) * 256 + t;
    int b = batch[i];
    if (i == 0) {
      for (int bb = 0; bb <= b; ++bb) start[bb] = 0;
    } else {
      int bp = batch[i - 1];
      for (int bb = bp + 1; bb <= b; ++bb) start[bb] = i;
    }
    if (i == NELEM - 1) {
      for (int bb = b + 1; bb <= BSETS; ++bb) start[bb] = NELEM;
    }
  } else if (blk == 1536) {               // ---- pe tables ----
    if (t < 18) {
      float out[64];
      pos_mlp40(t < 17 ? t : -1, ew1, eb1, eg, ebt, ew2, eb2, out);
      for (int o = 0; o < 64; ++o) enc_tab[t * 64 + o] = out[o];
    } else if (t >= 32 && t < 49) {
      float out[64];
      pos_mlp40(t - 32, dw1, db1, dg, dbt, dw2, db2, out);
      for (int o = 0; o < 64; ++o) dec_tab[(t - 32) * 64 + o] = out[o];
    }
  } else {                                // ---- weight swizzles (MFMA B-fragment layout) ----
    int idx = (blk - 1537) * 256 + t;
    if (idx < 6144) {   // dec_w1: 64x96, 2 ksteps x 6 ntiles
      int i = idx & 7, lane = (idx >> 3) & 63, rest = idx >> 9;
      int jt = rest % 6, s = rest / 6;
      int k = s * 32 + (lane >> 4) * 8 + i;
      int n = jt * 16 + (lane & 15);
      w1s[idx] = f2bf(decw1[k * 96 + n]);
    }
    int idx2 = idx - 6144;
    if (idx2 >= 0 && idx2 < 12288) {  // dec_w2: 96x128, 3 ksteps x 8 ntiles
      int i = idx2 & 7, lane = (idx2 >> 3) & 63, rest = idx2 >> 9;
      int jt = rest % 8, s = rest / 8;
      int k = s * 32 + (lane >> 4) * 8 + i;
      int n = jt * 16 + (lane & 15);
      w2s[idx2] = f2bf(decw2[k * 128 + n]);
    }
    int idx3 = idx - 18432;
    if (idx3 >= 0 && idx3 < 12288) {  // psi_w1: 128x96 hi/lo, 4 ksteps x 6 ntiles
      int i = idx3 & 7, lane = (idx3 >> 3) & 63, rest = idx3 >> 9;
      int jt = rest % 6, s = rest / 6;
      int k = s * 32 + (lane >> 4) * 8 + i;
      int n = jt * 16 + (lane & 15);
      float v = psiw1[k * 96 + n];
      unsigned short h = f2bf(v);
      pw1h[idx3] = h;
      pw1l[idx3] = f2bf(v - bf2f(h));
    }
    int idx4 = idx - 30720;
    if (idx4 >= 0 && idx4 < 6144) {   // psi_w2: 96x64 hi/lo, 3 ksteps x 4 ntiles
      int i = idx4 & 7, lane = (idx4 >> 3) & 63, rest = idx4 >> 9;
      int nt = rest % 4, s = rest / 4;
      int k = s * 32 + (lane >> 4) * 8 + i;
      int n = nt * 16 + (lane & 15);
      float v = psiw2[k * 64 + n];
      unsigned short h = f2bf(v);
      pw2h[idx4] = h;
      pw2l[idx4] = f2bf(v - bf2f(h));
    }
  }
}

// ---------------- encoder: fused rank + psi MLP via split-bf16 MFMA ----------------
// C = Ah*Bh + Ah*Bl + Al*Bh  (bf16 products exact in f32; rel err ~1e-5)
// wave w owns M-tile rows [w*16, w*16+16); LN done in MFMA C-layout via 16-lane shfl.
__global__ __launch_bounds__(256) void k_encoder(
    const float* __restrict__ x, const int* __restrict__ batch,
    const double* __restrict__ mag, const int* __restrict__ start,
    const unsigned short* __restrict__ w1h, const unsigned short* __restrict__ w1l,
    const float* __restrict__ b1, const float* __restrict__ g, const float* __restrict__ bt,
    const unsigned short* __restrict__ w2h, const unsigned short* __restrict__ w2l,
    const float* __restrict__ b2,
    const float* __restrict__ enc_tab, float* __restrict__ y1) {
  __shared__ float tt[64][100];   // stride 100 dwords: 16B-aligned rows, 2-way-bank-free
  __shared__ int pos_s[64];
  __shared__ int row_s[64];
  int t = threadIdx.x;
  int lane = t & 63;
  int w = __builtin_amdgcn_readfirstlane(t >> 6);
  int base = blockIdx.x * 64;
  int r = lane & 15, gq = lane >> 4;

  if (w == 0) {   // rank for the block's 64 rows (one lane per row)
    int gi = base + lane;
    int b = batch[gi];
    int segs = start[b], sege = start[b + 1];
    double mi = mag[gi];
    int kk = 0;
    for (int j = segs; j < sege; ++j) {
      double mj = mag[j];
      kk += (mj < mi) || (mj == mi && j < gi);
    }
    pos_s[lane] = segs + kk;
    row_s[lane] = kk < MAXP ? kk : MAXP;
  }

  // ---- A fragments: x rows of this wave's M-tile, split hi/lo ----
  const float* xr = x + (size_t)(base + w * 16 + r) * DIM + gq * 8;
  short8 ah[4], al[4];
#pragma unroll
  for (int s = 0; s < 4; ++s) {
    float4 v0 = *(const float4*)(xr + s * 32);
    float4 v1 = *(const float4*)(xr + s * 32 + 4);
    float vv[8] = {v0.x, v0.y, v0.z, v0.w, v1.x, v1.y, v1.z, v1.w};
#pragma unroll
    for (int i = 0; i < 8; ++i) {
      unsigned short h = f2bf(vv[i]);
      ((unsigned short*)&ah[s])[i] = h;
      ((unsigned short*)&al[s])[i] = f2bf(vv[i] - bf2f(h));
    }
  }

  // ---- GEMM1: h[64x96] ----
  const short8* W1H = (const short8*)w1h;
  const short8* W1L = (const short8*)w1l;
  f32x4 acc1[6] = {};
#pragma unroll
  for (int jt = 0; jt < 6; ++jt) {
#pragma unroll
    for (int s = 0; s < 4; ++s) {
      short8 bh = W1H[(s * 6 + jt) * 64 + lane];
      short8 bl = W1L[(s * 6 + jt) * 64 + lane];
      acc1[jt] = __builtin_amdgcn_mfma_f32_16x16x32_bf16(ah[s], bh, acc1[jt], 0, 0, 0);
      acc1[jt] = __builtin_amdgcn_mfma_f32_16x16x32_bf16(ah[s], bl, acc1[jt], 0, 0, 0);
      acc1[jt] = __builtin_amdgcn_mfma_f32_16x16x32_bf16(al[s], bh, acc1[jt], 0, 0, 0);
    }
  }

  // ---- bias + LN + tanh in C-layout: lane holds rows gq*4+reg, col jt*16+r ----
  float b1v[6], gv[6], btv[6];
#pragma unroll
  for (int jt = 0; jt < 6; ++jt) {
    b1v[jt] = b1[jt * 16 + r];
    gv[jt] = g[jt * 16 + r];
    btv[jt] = bt[jt * 16 + r];
  }
#pragma unroll
  for (int reg = 0; reg < 4; ++reg) {
    float h[6];
    float s1 = 0.f, s2 = 0.f;
#pragma unroll
    for (int jt = 0; jt < 6; ++jt) {
      h[jt] = acc1[jt][reg] + b1v[jt];
      s1 += h[jt]; s2 += h[jt] * h[jt];
    }
#pragma unroll
    for (int m = 1; m < 16; m <<= 1) {
      s1 += __shfl_xor(s1, m, 64);
      s2 += __shfl_xor(s2, m, 64);
    }
    float mean = s1 * (1.0f / 96.0f);
    float var = s2 * (1.0f / 96.0f) - mean * mean;
    float rs = rsqrtf(var + 1e-5f);
    int rowl = w * 16 + gq * 4 + reg;
#pragma unroll
    for (int jt = 0; jt < 6; ++jt)
      tt[rowl][jt * 16 + r] = fast_tanh((h[jt] - mean) * rs * gv[jt] + btv[jt]);
  }
  __syncthreads();

  // ---- A fragments for GEMM2 from tt (transpose via LDS), split hi/lo ----
  const float* trow = &tt[w * 16 + r][0] + gq * 8;
  short8 a2h[3], a2l[3];
#pragma unroll
  for (int s = 0; s < 3; ++s) {
    float4 u0 = *(const float4*)(trow + s * 32);
    float4 u1 = *(const float4*)(trow + s * 32 + 4);
    float vv[8] = {u0.x, u0.y, u0.z, u0.w, u1.x, u1.y, u1.z, u1.w};
#pragma unroll
    for (int i = 0; i < 8; ++i) {
      unsigned short h = f2bf(vv[i]);
      ((unsigned short*)&a2h[s])[i] = h;
      ((unsigned short*)&a2l[s])[i] = f2bf(vv[i] - bf2f(h));
    }
  }

  // ---- GEMM2: y[64x64] ----
  const short8* W2H = (const short8*)w2h;
  const short8* W2L = (const short8*)w2l;
  f32x4 acc2[4] = {};
#pragma unroll
  for (int nt = 0; nt < 4; ++nt) {
#pragma unroll
    for (int s = 0; s < 3; ++s) {
      short8 bh = W2H[(s * 4 + nt) * 64 + lane];
      short8 bl = W2L[(s * 4 + nt) * 64 + lane];
      acc2[nt] = __builtin_amdgcn_mfma_f32_16x16x32_bf16(a2h[s], bh, acc2[nt], 0, 0, 0);
      acc2[nt] = __builtin_amdgcn_mfma_f32_16x16x32_bf16(a2h[s], bl, acc2[nt], 0, 0, 0);
      acc2[nt] = __builtin_amdgcn_mfma_f32_16x16x32_bf16(a2l[s], bh, acc2[nt], 0, 0, 0);
    }
  }

  // ---- epilogue: bias, pe[rank] multiply, scatter to y1 ----
  float b2v[4];
#pragma unroll
  for (int nt = 0; nt < 4; ++nt) b2v[nt] = b2[nt * 16 + r];
#pragma unroll
  for (int reg = 0; reg < 4; ++reg) {
    int rowl = w * 16 + gq * 4 + reg;
    int pos = pos_s[rowl];
    const float* pe = enc_tab + row_s[rowl] * 64;
    float* yd = y1 + (size_t)pos * 64;
#pragma unroll
    for (int nt = 0; nt < 4; ++nt) {
      int col = nt * 16 + r;
      yd[col] = (acc2[nt][reg] + b2v[nt]) * pe[col];
    }
  }
}

// ---------------- phi (+fused segment-sum) + size_pred + argmax: 64 sets/block ----------------
__global__ __launch_bounds__(256) void k_phi(const float* __restrict__ y1,
                                             const int* __restrict__ start,
                                             const float* __restrict__ w1, const float* __restrict__ b1,
                                             const float* __restrict__ w2, const float* __restrict__ b2,
                                             const float* __restrict__ sw1, const float* __restrict__ sb1,
                                             const float* __restrict__ sw2, const float* __restrict__ sb2,
                                             float* __restrict__ z, int* __restrict__ ndec) {
  __shared__ float yt[64][65];
  __shared__ float tt[64][73];
  __shared__ float zt[64][65];
  __shared__ float st[64][41];
  int t = threadIdx.x;
  int base = blockIdx.x * 64;
  {  // fused segment sum: thread (set s = t>>2, chunk c = t&3), ascending-p order
    int s = t >> 2, c = t & 3;
    int sb = base + s;
    int ps = start[sb], pe = start[sb + 1];
    float acc[16];
#pragma unroll
    for (int i = 0; i < 16; ++i) acc[i] = 0.f;
    for (int p = ps; p < pe; ++p) {
      const float4* row = (const float4*)(y1 + (size_t)p * 64 + c * 16);
#pragma unroll
      for (int q = 0; q < 4; ++q) {
        float4 v = row[q];
        acc[4 * q] += v.x; acc[4 * q + 1] += v.y; acc[4 * q + 2] += v.z; acc[4 * q + 3] += v.w;
      }
    }
#pragma unroll
    for (int i = 0; i < 16; ++i) yt[s][c * 16 + i] = acc[i];
  }
  __syncthreads();
  int lane = t & 63;
  int w = __builtin_amdgcn_readfirstlane(t >> 6);
  int sb = base + lane;
  int nb = start[sb + 1] - start[sb];
  // layer1: 72 hidden = 4 waves x 18
  int j0 = w * 18;
  float acc[18];
#pragma unroll
  for (int jj = 0; jj < 18; ++jj) acc[jj] = b1[j0 + jj];
  for (int k = 0; k < 64; ++k) {
    float yv = yt[lane][k];
#pragma unroll
    for (int jj = 0; jj < 18; ++jj) acc[jj] += yv * w1[k * 72 + j0 + jj];
  }
  if (nb < MAXP) {
    const float* wr = w1 + (64 + nb) * 72 + j0;
#pragma unroll
    for (int jj = 0; jj < 18; ++jj) acc[jj] += wr[jj];
  }
#pragma unroll
  for (int jj = 0; jj < 18; ++jj) tt[lane][j0 + jj] = fast_tanh(acc[jj]);
  __syncthreads();
  // layer2: 64 out = 4 waves x 16
  int o0 = w * 16;
  float acc2[16];
#pragma unroll
  for (int oo = 0; oo < 16; ++oo) acc2[oo] = b2[o0 + oo];
  for (int j = 0; j < 72; ++j) {
    float tv = tt[lane][j];
#pragma unroll
    for (int oo = 0; oo < 16; ++oo) acc2[oo] += tv * w2[j * 64 + o0 + oo];
  }
  float4* zd = (float4*)(z + (size_t)sb * 64 + o0);
#pragma unroll
  for (int q = 0; q < 4; ++q)
    zd[q] = make_float4(acc2[4 * q], acc2[4 * q + 1], acc2[4 * q + 2], acc2[4 * q + 3]);
#pragma unroll
  for (int oo = 0; oo < 16; ++oo) zt[lane][o0 + oo] = acc2[oo];
  __syncthreads();
  // size_pred layer1: 40 hidden = 4 waves x 10
  int s0 = w * 10;
  float hs[10];
#pragma unroll
  for (int jj = 0; jj < 10; ++jj) hs[jj] = sb1[s0 + jj];
  for (int o = 0; o < 64; ++o) {
    float v = zt[lane][o];
#pragma unroll
    for (int jj = 0; jj < 10; ++jj) hs[jj] += v * sw1[o * 40 + s0 + jj];
  }
#pragma unroll
  for (int jj = 0; jj < 10; ++jj) st[lane][s0 + jj] = fast_tanh(hs[jj]);
  __syncthreads();
  // logits + argmax: wave 0 only
  if (w == 0) {
    float lg[17];
#pragma unroll
    for (int l = 0; l < 17; ++l) lg[l] = sb2[l];
    for (int j = 0; j < 40; ++j) {
      float tv = st[lane][j];
#pragma unroll
      for (int l = 0; l < 17; ++l) lg[l] += tv * sw2[j * 17 + l];
    }
    float best = lg[0]; int bi = 0;
#pragma unroll
    for (int l = 1; l < 17; ++l) if (lg[l] > best) { best = lg[l]; bi = l; }
    ndec[sb] = bi;
  }
}

// ---------------- decoder (+fused aux outputs): zp(64)->96 tanh->128, bf16 MFMA ----------------
__global__ __launch_bounds__(256) void k_decoder(
    const float* __restrict__ z, const float* __restrict__ dec_tab,
    const unsigned short* __restrict__ w1s, const unsigned short* __restrict__ w2s,
    const float* __restrict__ b1, const float* __restrict__ b2,
    const int* __restrict__ ndec, float* __restrict__ out0,
    float* __restrict__ out1, float* __restrict__ out2) {
  __shared__ __align__(16) unsigned short h2[64][104];
  int t = threadIdx.x;
  int lane = t & 63;
  int w = __builtin_amdgcn_readfirstlane(t >> 6);
  int quad = lane >> 4, m = lane & 15;
  int r = blockIdx.x * 64 + w * 16 + m;
  int b = r / 17, p = r - b * 17;
  const float4* z4 = (const float4*)(z + (size_t)b * 64);
  const float4* p4 = (const float4*)(dec_tab + p * 64);
  short8 a1[2];
#pragma unroll
  for (int s = 0; s < 2; ++s) {
    int q0 = (s * 32 + quad * 8) >> 2;
    float4 za = z4[q0], zb = z4[q0 + 1];
    float4 pa = p4[q0], pb = p4[q0 + 1];
    unsigned short* ap = (unsigned short*)&a1[s];
    ap[0] = f2bf(za.x * pa.x); ap[1] = f2bf(za.y * pa.y);
    ap[2] = f2bf(za.z * pa.z); ap[3] = f2bf(za.w * pa.w);
    ap[4] = f2bf(zb.x * pb.x); ap[5] = f2bf(zb.y * pb.y);
    ap[6] = f2bf(zb.z * pb.z); ap[7] = f2bf(zb.w * pb.w);
  }
  const short8* w1f = (const short8*)w1s;
  f32x4 acc[6] = {};
#pragma unroll
  for (int jt = 0; jt < 6; ++jt) {
    acc[jt] = __builtin_amdgcn_mfma_f32_16x16x32_bf16(a1[0], w1f[jt * 64 + lane], acc[jt], 0, 0, 0);
    acc[jt] = __builtin_amdgcn_mfma_f32_16x16x32_bf16(a1[1], w1f[(6 + jt) * 64 + lane], acc[jt], 0, 0, 0);
  }
#pragma unroll
  for (int jt = 0; jt < 6; ++jt) {
    int col = jt * 16 + m;
    float bias = b1[col];
#pragma unroll
    for (int reg = 0; reg < 4; ++reg) {
      int rl = w * 16 + quad * 4 + reg;
      h2[rl][col] = f2bf(fast_tanh(acc[jt][reg] + bias));
    }
  }
  __syncthreads();
  short8 a2[3];
#pragma unroll
  for (int s = 0; s < 3; ++s)
    a2[s] = *(const short8*)&h2[w * 16 + m][s * 32 + quad * 8];
  const short8* w2f = (const short8*)w2s;
  f32x4 acc2[8] = {};
#pragma unroll
  for (int nt = 0; nt < 8; ++nt) {
#pragma unroll
    for (int s = 0; s < 3; ++s)
      acc2[nt] = __builtin_amdgcn_mfma_f32_16x16x32_bf16(a2[s], w2f[(s * 8 + nt) * 64 + lane], acc2[nt], 0, 0, 0);
  }
  // hoisted per-row mask
  int rgbase = blockIdx.x * 64 + w * 16 + quad * 4;
  bool mk[4];
#pragma unroll
  for (int reg = 0; reg < 4; ++reg) {
    int rg = rgbase + reg;
    int bb = rg / 17, pp = rg - bb * 17;
    mk[reg] = (pp >= ndec[bb]);
  }
#pragma unroll
  for (int nt = 0; nt < 8; ++nt) {
    int n = nt * 16 + m;
    float bias = b2[n];
#pragma unroll
    for (int reg = 0; reg < 4; ++reg) {
      float v = acc2[nt][reg] + bias;
      if (mk[reg]) v = 0.0f;
      out0[(size_t)(rgbase + reg) * 128 + n] = v;
    }
  }
  if (t < 64) {   // fused aux outputs for this block's 64 rows
    int rg = blockIdx.x * 64 + t;
    int bb = rg / 17, pp = rg - bb * 17;
    out1[rg] = (float)bb;
    out2[rg] = (pp < ndec[bb]) ? 1.0f : 0.0f;
  }
}

extern "C" void kernel_launch(void* const* d_in, const int* in_sizes, int n_in,
                              void* d_out, int out_size, void* d_ws, size_t ws_size,
                              hipStream_t stream) {
  const float* x = (const float*)d_in[0];
  const int* batch = (const int*)d_in[1];
  const float* rank_w = (const float*)d_in[2];
  const float* rank_b = (const float*)d_in[3];
  const float* psi_w1 = (const float*)d_in[4];
  const float* psi_b1 = (const float*)d_in[5];
  const float* psi_g = (const float*)d_in[6];
  const float* psi_bt = (const float*)d_in[7];
  const float* psi_w2 = (const float*)d_in[8];
  const float* psi_b2 = (const float*)d_in[9];
  const float* pe_e_w1 = (const float*)d_in[10];
  const float* pe_e_b1 = (const float*)d_in[11];
  const float* pe_e_g = (const float*)d_in[12];
  const float* pe_e_bt = (const float*)d_in[13];
  const float* pe_e_w2 = (const float*)d_in[14];
  const float* pe_e_b2 = (const float*)d_in[15];
  const float* phi_w1 = (const float*)d_in[16];
  const float* phi_b1 = (const float*)d_in[17];
  const float* phi_w2 = (const float*)d_in[18];
  const float* phi_b2 = (const float*)d_in[19];
  const float* size_w1 = (const float*)d_in[20];
  const float* size_b1 = (const float*)d_in[21];
  const float* size_w2 = (const float*)d_in[22];
  const float* size_b2 = (const float*)d_in[23];
  const float* pe_d_w1 = (const float*)d_in[24];
  const float* pe_d_b1 = (const float*)d_in[25];
  const float* pe_d_g = (const float*)d_in[26];
  const float* pe_d_bt = (const float*)d_in[27];
  const float* pe_d_w2 = (const float*)d_in[28];
  const float* pe_d_b2 = (const float*)d_in[29];
  const float* dec_w1 = (const float*)d_in[30];
  const float* dec_b1 = (const float*)d_in[31];
  const float* dec_w2 = (const float*)d_in[32];
  const float* dec_b2 = (const float*)d_in[33];

  char* ws = (char*)d_ws;
  int* start = (int*)(ws);                                   // 131076 B
  double* mag = (double*)(ws + 0x40000);                     // 1 MB
  float* enc_tab = (float*)(ws + 0x1C0000);
  float* dec_tab = (float*)(ws + 0x1C2000);
  unsigned short* w1s = (unsigned short*)(ws + 0x1C4000);    // 12 KB
  unsigned short* w2s = (unsigned short*)(ws + 0x1C8000);    // 24 KB
  unsigned short* pw1h = (unsigned short*)(ws + 0x1CE000);   // 24 KB
  unsigned short* pw1l = (unsigned short*)(ws + 0x1D4000);   // 24 KB
  unsigned short* pw2h = (unsigned short*)(ws + 0x1DA000);   // 12 KB
  unsigned short* pw2l = (unsigned short*)(ws + 0x1DD000);   // 12 KB
  float* zbuf = (float*)(ws + 0x200000);                     // 8 MB (live during decoder)
  int* ndec = (int*)(ws + 0xA00000);                         // 128 KB

  float* out0 = (float*)d_out;
  float* out1 = out0 + 71303168;    // B*17*128
  float* out2 = out1 + 557056;      // B*17

  // y1 scratch inside out0: consumed by k_phi before k_decoder overwrites out0
  float* y1 = out0;                  // NELEM*64 f32 = 32 MB

  k_init<<<1681, 256, 0, stream>>>(x, batch, rank_w, rank_b, mag, start,
                                   pe_e_w1, pe_e_b1, pe_e_g, pe_e_bt, pe_e_w2, pe_e_b2,
                                   pe_d_w1, pe_d_b1, pe_d_g, pe_d_bt, pe_d_w2, pe_d_b2,
                                   enc_tab, dec_tab, dec_w1, dec_w2, w1s, w2s,
                                   psi_w1, psi_w2, pw1h, pw1l, pw2h, pw2l);
  k_encoder<<<2048, 256, 0, stream>>>(x, batch, mag, start, pw1h, pw1l,
                                      psi_b1, psi_g, psi_bt, pw2h, pw2l, psi_b2,
                                      enc_tab, y1);
  k_phi<<<512, 256, 0, stream>>>(y1, start, phi_w1, phi_b1, phi_w2, phi_b2,
                                 size_w1, size_b1, size_w2, size_b2, zbuf, ndec);
  k_decoder<<<8704, 256, 0, stream>>>(zbuf, dec_tab, w1s, w2s, dec_b1, dec_b2, ndec,
                                      out0, out1, out2);
}